// Round 5
// baseline (1005.982 us; speedup 1.0000x reference)
//
#include <hip/hip_runtime.h>
#include <cstdint>
#include <cstddef>

// Problem constants (fixed by the reference)
#define NN   50000
#define MM   24
#define FNIN 92
#define FEIN 41
#define NBLK 3125            // NN / 16 nodes per conv block
#define EROW 48              // edge row padded 41 -> 48 bf16 (96 B)
#define ETILE (MM * 16 * EROW)  // 18432 elems per node-block tile

typedef __attribute__((ext_vector_type(8))) short bf16x8;
typedef __attribute__((ext_vector_type(4))) float f32x4;
typedef __attribute__((ext_vector_type(8))) unsigned short u16x8;

__device__ __forceinline__ unsigned short f2bf(float x) {
    unsigned int u = __float_as_uint(x);
    return (unsigned short)((u + 0x7fffu + ((u >> 16) & 1u)) >> 16);  // RNE
}
__device__ __forceinline__ float bf2f(unsigned short h) {
    return __uint_as_float(((unsigned int)h) << 16);
}

// Pair-interleaved P layout: P[node][2*c+0]=filter col c, P[node][2*c+1]=core col c.
// Pn has a sentinel row at node==NN: filter=-1e30 (sigmoid -> +0), core=0, so
// padded neighbors contribute exactly 0 with NO mask ops in the inner loop.

// ---------------------------------------------------------------------------
// prep: build per-layer combined weights in MFMA B-fragment order + Pn sentinel.
//   WcB_l : B[k][n] = (We @ W_l[128:192])[k][n], k<41 else 0.  (8 j-tiles x 2 ksteps)
//   WsnBhi/lo_l: split-bf16 of B[k][n] = W_l[k][n] (n<128, ->Ps) /
//                W_l[64+k][n-128] (->Pn). (16 j-tiles)
//   bias_c_l[n] = b_l[n] + (be @ W_l[128:192])[n]
// Fragment elem layout: idx = ((j*2+s)*64 + lane)*8 + t ; k = s*32 + (lane>>4)*8 + t ;
//                       n = 16*j + (lane&15)
// ---------------------------------------------------------------------------
__global__ __launch_bounds__(256) void prep_kernel(
    const float* __restrict__ We, const float* __restrict__ be,
    const float* __restrict__ W1, const float* __restrict__ b1,
    const float* __restrict__ W2, const float* __restrict__ b2,
    const float* __restrict__ W3, const float* __restrict__ b3,
    unsigned short* __restrict__ WcB,
    unsigned short* __restrict__ WsnBhi, unsigned short* __restrict__ WsnBlo,
    float* __restrict__ bias_c, float* __restrict__ Pn)
{
    int l = blockIdx.x / 24;
    int part = blockIdx.x % 24;
    const float* W  = (l == 0) ? W1 : (l == 1) ? W2 : W3;
    const float* bl = (l == 0) ? b1 : (l == 1) ? b2 : b3;
    int tid = threadIdx.x;
    if (blockIdx.x == 0 && tid < 128) {
        // sentinel row: filter (even) = -1e30, core (odd) = 0
        Pn[(size_t)NN * 128 + tid] = (tid & 1) ? 0.f : -1e30f;
    }
    if (part < 8) {
        int j = part;
        for (int e = tid; e < 1024; e += 256) {
            int s = e >> 9, L = (e >> 3) & 63, t = e & 7;
            int k = s * 32 + ((L >> 4) << 3) + t;
            int n = 16 * j + (L & 15);
            float v = 0.f;
            if (k < FEIN) {
                for (int i = 0; i < 64; ++i)
                    v += We[k * 64 + i] * W[(128 + i) * 128 + n];
            }
            WcB[l * 8192 + j * 1024 + e] = f2bf(v);
        }
        if (part == 0 && tid < 128) {
            float v = bl[tid];
            for (int i = 0; i < 64; ++i)
                v += be[i] * W[(128 + i) * 128 + tid];
            bias_c[l * 128 + tid] = v;
        }
    } else {
        int j = part - 8;
        for (int e = tid; e < 1024; e += 256) {
            int s = e >> 9, L = (e >> 3) & 63, t = e & 7;
            int k = s * 32 + ((L >> 4) << 3) + t;
            int n = 16 * j + (L & 15);
            float v = (n < 128) ? W[k * 128 + n] : W[(64 + k) * 128 + (n - 128)];
            unsigned short h = f2bf(v);
            WsnBhi[l * 16384 + j * 1024 + e] = h;
            WsnBlo[l * 16384 + j * 1024 + e] = f2bf(v - bf2f(h));
        }
    }
}

// ---------------------------------------------------------------------------
// cast: edge_fea (N,M,41) fp32 -> block-tiled bf16, m-major rows, k padded
// to 48. 8 nodes per block: coalesced float4 read -> LDS -> transposed ushort8
// (16 B) stores. No per-element division by 48.
// ---------------------------------------------------------------------------
#define CN 8                      // nodes per cast block
__global__ __launch_bounds__(256) void cast_kernel(
    const float* __restrict__ edge_fea, unsigned short* __restrict__ edge_tiles)
{
    __shared__ float s[CN * MM * FEIN];   // 7872 floats = 31.5 KB
    int B = blockIdx.x;
    int b = B >> 1, half = B & 1;
    const float4* src = (const float4*)(edge_fea + ((size_t)b * 16 + half * CN) * (MM * FEIN));
    float4* sd = (float4*)s;
    for (int i = threadIdx.x; i < (CN * MM * FEIN) / 4; i += 256)
        sd[i] = src[i];
    __syncthreads();
    unsigned short* dst = edge_tiles + (size_t)b * ETILE;
    for (int c = threadIdx.x; c < CN * MM * 6; c += 256) {   // 6 chunks of 8 per row
        int r = c / 6, cc = c - r * 6;
        int m = r >> 3, nbl = r & 7;          // 192 rows: m-major over 8 local nodes
        int k0 = cc * 8;
        const float* srow = &s[(nbl * MM + m) * FEIN];
        u16x8 v;
        #pragma unroll
        for (int j = 0; j < 8; ++j) {
            int k = k0 + j;
            v[j] = (k < FEIN) ? f2bf(srow[k]) : (unsigned short)0;
        }
        *(u16x8*)(dst + (size_t)(m * 16 + half * CN + nbl) * EROW + k0) = v;
    }
}

// ---------------------------------------------------------------------------
// embed: node0 = node_fea @ Wn + bn   (50000x92 @ 92x64), fp32 VALU (exact).
// k-outer with 16 register accumulators: 17 LDS reads per 16 FMAs.
// ---------------------------------------------------------------------------
__global__ __launch_bounds__(256) void embed_kernel(
    const float* __restrict__ node_fea, const float* __restrict__ Wn,
    const float* __restrict__ bn, float* __restrict__ node_out)
{
    __shared__ float w_s[FNIN * 64];
    __shared__ float f_s[64 * FNIN];
    int tid = threadIdx.x;
    int base = blockIdx.x * 64;
    int cnt = min(64, NN - base);
    for (int i = tid; i < FNIN * 64; i += 256) w_s[i] = Wn[i];
    for (int i = tid; i < cnt * FNIN; i += 256) f_s[i] = node_fea[base * FNIN + i];
    __syncthreads();
    int c = tid & 63, g = tid >> 6;
    float acc[16];
    #pragma unroll
    for (int jj = 0; jj < 16; ++jj) acc[jj] = 0.f;
    for (int k = 0; k < FNIN; ++k) {
        float wv = w_s[k * 64 + c];               // conflict-free
        #pragma unroll
        for (int jj = 0; jj < 16; ++jj)
            acc[jj] += f_s[(g + 4 * jj) * FNIN + k] * wv;   // wave-broadcast
    }
    float bv = bn[c];
    #pragma unroll
    for (int jj = 0; jj < 16; ++jj) {
        int n = g + 4 * jj;
        if (n < cnt) node_out[(base + n) * 64 + c] = acc[jj] + bv;
    }
}

// ---------------------------------------------------------------------------
// p: P = node @ [W_s | W_n] -> Ps (N x 128 fp32), Pn (N x 128 fp32), both in
// pair-interleaved layout (filter/core adjacent), written as float2.
// Split-bf16 MFMA: x = hi + lo, P = Ahi*Bhi + Alo*Bhi + Ahi*Blo  (~fp32 accurate).
// Block = 64 nodes, wave w owns M-tile rows 16w..16w+15. 8 paired j-tiles:
// pair jp<4 -> Ps tiles (jp, jp+4); jp>=4 -> Pn tiles (jp+4, jp+8).
// ---------------------------------------------------------------------------
__global__ __launch_bounds__(256) void p_kernel(
    const float* __restrict__ node,
    const unsigned short* __restrict__ Bhi, const unsigned short* __restrict__ Blo,
    float* __restrict__ Ps, float* __restrict__ Pn)
{
    __shared__ float n_s[64 * 68];          // stride 68 floats: 2-way LDS aliasing only
    int tid = threadIdx.x;
    int base = blockIdx.x * 64;
    int cnt = min(64, NN - base);
    for (int i = tid; i < cnt * 64; i += 256) {
        int r = i >> 6, c = i & 63;
        n_s[r * 68 + c] = node[base * 64 + i];
    }
    __syncthreads();
    int w = tid >> 6, L = tid & 63, quad = L >> 4, lc = L & 15;
    const float* ap = &n_s[(16 * w + lc) * 68 + quad * 8];
    bf16x8 a0h, a0l, a1h, a1l;
    for (int t = 0; t < 8; ++t) {
        float x0 = ap[t];                   // k = quad*8 + t
        float x1 = ap[32 + t];              // k = 32 + quad*8 + t
        unsigned short h0 = f2bf(x0), h1 = f2bf(x1);
        a0h[t] = (short)h0; a1h[t] = (short)h1;
        a0l[t] = (short)f2bf(x0 - bf2f(h0));
        a1l[t] = (short)f2bf(x1 - bf2f(h1));
    }
    const bf16x8* bh = (const bf16x8*)Bhi;
    const bf16x8* bl = (const bf16x8*)Blo;
    #pragma unroll
    for (int jp = 0; jp < 8; ++jp) {
        int jf = (jp < 4) ? jp : (jp + 4);       // filter tile
        int jc = jf + 4;                         // core tile
        bf16x8 f0h = bh[(jf * 2 + 0) * 64 + L];
        bf16x8 f1h = bh[(jf * 2 + 1) * 64 + L];
        bf16x8 f0l = bl[(jf * 2 + 0) * 64 + L];
        bf16x8 f1l = bl[(jf * 2 + 1) * 64 + L];
        bf16x8 c0h = bh[(jc * 2 + 0) * 64 + L];
        bf16x8 c1h = bh[(jc * 2 + 1) * 64 + L];
        bf16x8 c0l = bl[(jc * 2 + 0) * 64 + L];
        bf16x8 c1l = bl[(jc * 2 + 1) * 64 + L];
        f32x4 Cf = {0.f, 0.f, 0.f, 0.f}, Cc = {0.f, 0.f, 0.f, 0.f};
        Cf = __builtin_amdgcn_mfma_f32_16x16x32_bf16(a0h, f0h, Cf, 0, 0, 0);
        Cf = __builtin_amdgcn_mfma_f32_16x16x32_bf16(a1h, f1h, Cf, 0, 0, 0);
        Cf = __builtin_amdgcn_mfma_f32_16x16x32_bf16(a0l, f0h, Cf, 0, 0, 0);
        Cf = __builtin_amdgcn_mfma_f32_16x16x32_bf16(a1l, f1h, Cf, 0, 0, 0);
        Cf = __builtin_amdgcn_mfma_f32_16x16x32_bf16(a0h, f0l, Cf, 0, 0, 0);
        Cf = __builtin_amdgcn_mfma_f32_16x16x32_bf16(a1h, f1l, Cf, 0, 0, 0);
        Cc = __builtin_amdgcn_mfma_f32_16x16x32_bf16(a0h, c0h, Cc, 0, 0, 0);
        Cc = __builtin_amdgcn_mfma_f32_16x16x32_bf16(a1h, c1h, Cc, 0, 0, 0);
        Cc = __builtin_amdgcn_mfma_f32_16x16x32_bf16(a0l, c0h, Cc, 0, 0, 0);
        Cc = __builtin_amdgcn_mfma_f32_16x16x32_bf16(a1l, c1h, Cc, 0, 0, 0);
        Cc = __builtin_amdgcn_mfma_f32_16x16x32_bf16(a0h, c0l, Cc, 0, 0, 0);
        Cc = __builtin_amdgcn_mfma_f32_16x16x32_bf16(a1h, c1l, Cc, 0, 0, 0);
        int cl = (jp < 4) ? (16 * jp + lc) : (16 * (jp - 4) + lc);   // col in [0,64)
        float* P = (jp < 4) ? Ps : Pn;
        #pragma unroll
        for (int r = 0; r < 4; ++r) {
            int nr = 16 * w + quad * 4 + r;  // C layout: row = quad*4 + reg
            if (nr < cnt) {
                float2 v = {Cf[r], Cc[r]};
                *(float2*)&P[(size_t)(base + nr) * 128 + 2 * cl] = v;
            }
        }
    }
}

// ---------------------------------------------------------------------------
// conv: one layer. Block = 16 nodes. Fully-unrolled m-loop over 24 neighbors,
// depth-2 slot pipeline. Per m:
//   C_edge(16 nodes x 128) = edge_tile_m @ Wc  (2 MFMA ksteps, K pad zeros in B)
//   gated = C_edge + Ps[self] + Pn[idx] + bias ; acc += sig(f)*softplus(c)
// Padded neighbors read the Pn sentinel row (filter=-1e30 -> sigmoid=+0) so no
// mask ops exist in the loop. Gather = ds_read(precomputed gg<<9) + v_add +
// saddr-form dwordx2. idx offsets in LDS at stride 25 (conflict-free broadcast).
// ---------------------------------------------------------------------------
__global__ __launch_bounds__(256) void conv_kernel(
    const float* __restrict__ node_in, const int* __restrict__ idx,
    const unsigned short* __restrict__ edge_tiles,
    const float* __restrict__ Ps, const float* __restrict__ Pn,
    const unsigned short* __restrict__ WcB, const float* __restrict__ bias_c,
    const float* __restrict__ alpha_p, float* __restrict__ node_out)
{
    __shared__ unsigned ofs_s[16 * 25];     // (gg<<9) per (node,m); stride 25
    int tid = threadIdx.x;
    int b = blockIdx.x;
    int base = b * 16;
    for (int i = tid; i < 16 * MM; i += 256) {
        int row = i / MM, m = i - row * MM;
        int g = idx[base * MM + i];
        unsigned gg = (unsigned)((g >= 0) ? g : NN);   // NN = sentinel row
        ofs_s[row * 25 + m] = gg << 9;                 // byte offset of Pn row
    }
    __syncthreads();

    int w = tid >> 6, L = tid & 63, quad = L >> 4, lc = L & 15;
    int colf = 16 * w + lc;                  // filter col (0..63) == output col
    const bf16x8* wcb = (const bf16x8*)WcB;
    bf16x8 bf0 = wcb[(w * 2 + 0) * 64 + L];        // filter tile j=w, kstep 0
    bf16x8 bf1 = wcb[(w * 2 + 1) * 64 + L];        // kstep 1 (k>=48 rows are zero)
    bf16x8 bc0 = wcb[((w + 4) * 2 + 0) * 64 + L];  // core tile j=w+4
    bf16x8 bc1 = wcb[((w + 4) * 2 + 1) * 64 + L];

    float bias_f = bias_c[colf];
    float bias_g = bias_c[64 + colf];
    float psb_f[4], psb_c[4];
    #pragma unroll
    for (int r = 0; r < 4; ++r) {
        int nr = base + quad * 4 + r;
        float2 sp = *(const float2*)&Ps[(size_t)nr * 128 + 2 * colf];
        psb_f[r] = sp.x + bias_f;
        psb_c[r] = sp.y + bias_g;
    }

    float acc[4] = {0.f, 0.f, 0.f, 0.f};
    const char* PnB = (const char*)Pn;
    unsigned coff = (unsigned)colf << 3;     // byte offset of the float2 pair in a row
    const unsigned* ofsr = &ofs_s[quad * 100];   // rows quad*4..+3, stride 25
    // A-frag base: row = lc, chunk = quad (kstep1 may read past the 48-elem row
    // for quad>=2 -- finite garbage nullified by zero B rows k>=48).
    const unsigned short* et = edge_tiles + (size_t)b * ETILE + lc * EROW + quad * 8;

    float2 pn_pf[2][4];
    bf16x8 a0_pf[2], a1_pf[2];

#define CONV_FETCH(slot, mm) do {                                              \
        _Pragma("unroll")                                                      \
        for (int r = 0; r < 4; ++r) {                                          \
            unsigned o = ofsr[r * 25 + (mm)] + coff;                           \
            pn_pf[slot][r] = *(const float2*)(PnB + o);                        \
        }                                                                      \
        const unsigned short* ep = et + (mm) * (16 * EROW);                    \
        a0_pf[slot] = *(const bf16x8*)(ep);                                    \
        a1_pf[slot] = *(const bf16x8*)(ep + 32);                               \
    } while (0)

    CONV_FETCH(0, 0);
    CONV_FETCH(1, 1);

    #pragma unroll
    for (int m = 0; m < MM; ++m) {
        int s = m & 1;
        bf16x8 a0 = a0_pf[s], a1 = a1_pf[s];
        float2 pnl[4];
        #pragma unroll
        for (int r = 0; r < 4; ++r) pnl[r] = pn_pf[s][r];
        if (m + 2 < MM) CONV_FETCH(s, m + 2);
        f32x4 Cf = {0.f, 0.f, 0.f, 0.f}, Cc = {0.f, 0.f, 0.f, 0.f};
        Cf = __builtin_amdgcn_mfma_f32_16x16x32_bf16(a0, bf0, Cf, 0, 0, 0);
        Cf = __builtin_amdgcn_mfma_f32_16x16x32_bf16(a1, bf1, Cf, 0, 0, 0);
        Cc = __builtin_amdgcn_mfma_f32_16x16x32_bf16(a0, bc0, Cc, 0, 0, 0);
        Cc = __builtin_amdgcn_mfma_f32_16x16x32_bf16(a1, bc1, Cc, 0, 0, 0);
        #pragma unroll
        for (int r = 0; r < 4; ++r) {
            float gf = Cf[r] + psb_f[r] + pnl[r].x;
            float gc = Cc[r] + psb_c[r] + pnl[r].y;
            float sg = 1.0f / (1.0f + __expf(-gf));   // sentinel: 1/(1+inf) = +0
            float sp = fmaxf(gc, 0.f) + __logf(1.0f + __expf(-fabsf(gc)));
            acc[r] += sg * sp;
        }
    }
#undef CONV_FETCH

    float alpha = alpha_p[0];
    #pragma unroll
    for (int r = 0; r < 4; ++r) {
        int nr = base + quad * 4 + r;
        float x = alpha * node_in[nr * 64 + colf] + acc[r];
        float o = fmaxf(x, 0.f) + __logf(1.0f + __expf(-fabsf(x)));
        node_out[nr * 64 + colf] = o;
    }
}

// ---------------------------------------------------------------------------
extern "C" void kernel_launch(void* const* d_in, const int* in_sizes, int n_in,
                              void* d_out, int out_size, void* d_ws, size_t ws_size,
                              hipStream_t stream)
{
    const float* node_fea = (const float*)d_in[0];
    const float* edge_fea = (const float*)d_in[1];
    const int*   eidx     = (const int*)d_in[2];
    const float* Wn = (const float*)d_in[3];
    const float* bn = (const float*)d_in[4];
    const float* We = (const float*)d_in[5];
    const float* be = (const float*)d_in[6];
    const float* W1 = (const float*)d_in[7];
    const float* b1 = (const float*)d_in[8];
    const float* a1 = (const float*)d_in[9];
    const float* W2 = (const float*)d_in[10];
    const float* b2 = (const float*)d_in[11];
    const float* a2 = (const float*)d_in[12];
    const float* W3 = (const float*)d_in[13];
    const float* b3 = (const float*)d_in[14];
    const float* a3 = (const float*)d_in[15];
    float* out = (float*)d_out;

    // Workspace layout (~192 MiB total)
    char* ws = (char*)d_ws;
    unsigned short* edge_tiles = (unsigned short*)ws;   // 115,200,000 B + 256 pad
    size_t off = 115200256;
    float* nodeA = (float*)(ws + off); off += 12800000;
    float* nodeB = (float*)(ws + off); off += 12800000;
    float* Ps = (float*)(ws + off); off += 25600000;
    float* Pn = (float*)(ws + off); off += 25600512;    // +512 B sentinel row
    unsigned short* WcB    = (unsigned short*)(ws + off); off += 3 * 8192 * 2;
    unsigned short* WsnBhi = (unsigned short*)(ws + off); off += 3 * 16384 * 2;
    unsigned short* WsnBlo = (unsigned short*)(ws + off); off += 3 * 16384 * 2;
    float* bias_c = (float*)(ws + off); off += 3 * 128 * 4;

    prep_kernel<<<dim3(72), dim3(256), 0, stream>>>(We, be, W1, b1, W2, b2, W3, b3,
                                                    WcB, WsnBhi, WsnBlo, bias_c, Pn);
    cast_kernel<<<dim3(2 * NBLK), dim3(256), 0, stream>>>(edge_fea, edge_tiles);
    embed_kernel<<<dim3(782), dim3(256), 0, stream>>>(node_fea, Wn, bn, nodeA);

    p_kernel<<<dim3(782), dim3(256), 0, stream>>>(nodeA, WsnBhi, WsnBlo, Ps, Pn);
    conv_kernel<<<dim3(NBLK), dim3(256), 0, stream>>>(nodeA, eidx, edge_tiles, Ps, Pn,
                                                      WcB, bias_c, a1, nodeB);

    p_kernel<<<dim3(782), dim3(256), 0, stream>>>(nodeB, WsnBhi + 16384, WsnBlo + 16384, Ps, Pn);
    conv_kernel<<<dim3(NBLK), dim3(256), 0, stream>>>(nodeB, eidx, edge_tiles, Ps, Pn,
                                                      WcB + 8192, bias_c + 128, a2, nodeA);

    p_kernel<<<dim3(782), dim3(256), 0, stream>>>(nodeA, WsnBhi + 32768, WsnBlo + 32768, Ps, Pn);
    conv_kernel<<<dim3(NBLK), dim3(256), 0, stream>>>(nodeA, eidx, edge_tiles, Ps, Pn,
                                                      WcB + 16384, bias_c + 256, a3, out);
}

// Round 6
// 732.487 us; speedup vs baseline: 1.3734x; 1.3734x over previous
//
#include <hip/hip_runtime.h>
#include <cstdint>
#include <cstddef>

// Problem constants (fixed by the reference)
#define NN   50000
#define MM   24
#define FNIN 92
#define FEIN 41
#define NBLK 3125            // NN / 16 nodes per conv block
#define EROW 48              // edge row padded 41 -> 48 bf16 (96 B)
#define ETILE (MM * 16 * EROW)  // 18432 elems per node-block tile

typedef __attribute__((ext_vector_type(8))) short bf16x8;
typedef __attribute__((ext_vector_type(4))) float f32x4;
typedef __attribute__((ext_vector_type(8))) unsigned short u16x8;
typedef __attribute__((ext_vector_type(2))) _Float16 f16x2;

__device__ __forceinline__ unsigned short f2bf(float x) {
    unsigned int u = __float_as_uint(x);
    return (unsigned short)((u + 0x7fffu + ((u >> 16) & 1u)) >> 16);  // RNE
}
__device__ __forceinline__ float bf2f(unsigned short h) {
    return __uint_as_float(((unsigned int)h) << 16);
}
__device__ __forceinline__ _Float16 f2h_clamp(float x) {
    return (_Float16)fminf(fmaxf(x, -60000.f), 60000.f);   // stay finite in fp16
}

// P layout: fp16 pair-interleaved, P[node][2*c+0]=filter col c, [2*c+1]=core col c.
// Row = 128 halves = 256 B. Pn sentinel row at node==NN: filter=-60000 (exp
// overflows -> sigmoid=+0), core=0 -> padded neighbors contribute exactly 0,
// no mask ops in the conv inner loop.

// ---------------------------------------------------------------------------
// prep: build per-layer combined weights in MFMA B-fragment order + Pn sentinel.
//   WcB_l : B[k][n] = (We @ W_l[128:192])[k][n], k<41 else 0.  (8 j-tiles x 2 ksteps)
//   WsnBhi/lo_l: split-bf16 of B[k][n] = W_l[k][n] (n<128, ->Ps) /
//                W_l[64+k][n-128] (->Pn). (16 j-tiles)
//   bias_c_l[n] = b_l[n] + (be @ W_l[128:192])[n]
// Fragment elem layout: idx = ((j*2+s)*64 + lane)*8 + t ; k = s*32 + (lane>>4)*8 + t ;
//                       n = 16*j + (lane&15)
// ---------------------------------------------------------------------------
__global__ __launch_bounds__(256) void prep_kernel(
    const float* __restrict__ We, const float* __restrict__ be,
    const float* __restrict__ W1, const float* __restrict__ b1,
    const float* __restrict__ W2, const float* __restrict__ b2,
    const float* __restrict__ W3, const float* __restrict__ b3,
    unsigned short* __restrict__ WcB,
    unsigned short* __restrict__ WsnBhi, unsigned short* __restrict__ WsnBlo,
    float* __restrict__ bias_c, _Float16* __restrict__ Pn)
{
    int l = blockIdx.x / 24;
    int part = blockIdx.x % 24;
    const float* W  = (l == 0) ? W1 : (l == 1) ? W2 : W3;
    const float* bl = (l == 0) ? b1 : (l == 1) ? b2 : b3;
    int tid = threadIdx.x;
    if (blockIdx.x == 0 && tid < 128) {
        // sentinel row: filter (even) = -60000, core (odd) = 0
        Pn[(size_t)NN * 128 + tid] = (tid & 1) ? (_Float16)0.f : (_Float16)(-60000.f);
    }
    if (part < 8) {
        int j = part;
        for (int e = tid; e < 1024; e += 256) {
            int s = e >> 9, L = (e >> 3) & 63, t = e & 7;
            int k = s * 32 + ((L >> 4) << 3) + t;
            int n = 16 * j + (L & 15);
            float v = 0.f;
            if (k < FEIN) {
                for (int i = 0; i < 64; ++i)
                    v += We[k * 64 + i] * W[(128 + i) * 128 + n];
            }
            WcB[l * 8192 + j * 1024 + e] = f2bf(v);
        }
        if (part == 0 && tid < 128) {
            float v = bl[tid];
            for (int i = 0; i < 64; ++i)
                v += be[i] * W[(128 + i) * 128 + tid];
            bias_c[l * 128 + tid] = v;
        }
    } else {
        int j = part - 8;
        for (int e = tid; e < 1024; e += 256) {
            int s = e >> 9, L = (e >> 3) & 63, t = e & 7;
            int k = s * 32 + ((L >> 4) << 3) + t;
            int n = 16 * j + (L & 15);
            float v = (n < 128) ? W[k * 128 + n] : W[(64 + k) * 128 + (n - 128)];
            unsigned short h = f2bf(v);
            WsnBhi[l * 16384 + j * 1024 + e] = h;
            WsnBlo[l * 16384 + j * 1024 + e] = f2bf(v - bf2f(h));
        }
    }
}

// ---------------------------------------------------------------------------
// cast: edge_fea (N,M,41) fp32 -> block-tiled bf16, m-major rows, k padded
// to 48. 8 nodes per block: coalesced float4 read -> LDS -> transposed ushort8
// (16 B) stores. No per-element division by 48.
// ---------------------------------------------------------------------------
#define CN 8                      // nodes per cast block
__global__ __launch_bounds__(256) void cast_kernel(
    const float* __restrict__ edge_fea, unsigned short* __restrict__ edge_tiles)
{
    __shared__ float s[CN * MM * FEIN];   // 7872 floats = 31.5 KB
    int B = blockIdx.x;
    int b = B >> 1, half = B & 1;
    const float4* src = (const float4*)(edge_fea + ((size_t)b * 16 + half * CN) * (MM * FEIN));
    float4* sd = (float4*)s;
    for (int i = threadIdx.x; i < (CN * MM * FEIN) / 4; i += 256)
        sd[i] = src[i];
    __syncthreads();
    unsigned short* dst = edge_tiles + (size_t)b * ETILE;
    for (int c = threadIdx.x; c < CN * MM * 6; c += 256) {   // 6 chunks of 8 per row
        int r = c / 6, cc = c - r * 6;
        int m = r >> 3, nbl = r & 7;          // 192 rows: m-major over 8 local nodes
        int k0 = cc * 8;
        const float* srow = &s[(nbl * MM + m) * FEIN];
        u16x8 v;
        #pragma unroll
        for (int j = 0; j < 8; ++j) {
            int k = k0 + j;
            v[j] = (k < FEIN) ? f2bf(srow[k]) : (unsigned short)0;
        }
        *(u16x8*)(dst + (size_t)(m * 16 + half * CN + nbl) * EROW + k0) = v;
    }
}

// ---------------------------------------------------------------------------
// embed: node0 = node_fea @ Wn + bn   (50000x92 @ 92x64), fp32 VALU (exact).
// k-outer with 16 register accumulators: 17 LDS reads per 16 FMAs.
// ---------------------------------------------------------------------------
__global__ __launch_bounds__(256) void embed_kernel(
    const float* __restrict__ node_fea, const float* __restrict__ Wn,
    const float* __restrict__ bn, float* __restrict__ node_out)
{
    __shared__ float w_s[FNIN * 64];
    __shared__ float f_s[64 * FNIN];
    int tid = threadIdx.x;
    int base = blockIdx.x * 64;
    int cnt = min(64, NN - base);
    for (int i = tid; i < FNIN * 64; i += 256) w_s[i] = Wn[i];
    for (int i = tid; i < cnt * FNIN; i += 256) f_s[i] = node_fea[base * FNIN + i];
    __syncthreads();
    int c = tid & 63, g = tid >> 6;
    float acc[16];
    #pragma unroll
    for (int jj = 0; jj < 16; ++jj) acc[jj] = 0.f;
    for (int k = 0; k < FNIN; ++k) {
        float wv = w_s[k * 64 + c];               // conflict-free
        #pragma unroll
        for (int jj = 0; jj < 16; ++jj)
            acc[jj] += f_s[(g + 4 * jj) * FNIN + k] * wv;   // wave-broadcast
    }
    float bv = bn[c];
    #pragma unroll
    for (int jj = 0; jj < 16; ++jj) {
        int n = g + 4 * jj;
        if (n < cnt) node_out[(base + n) * 64 + c] = acc[jj] + bv;
    }
}

// ---------------------------------------------------------------------------
// p: P = node @ [W_s | W_n] -> Ps (N x 128 fp16), Pn (N x 128 fp16), both in
// pair-interleaved layout (filter/core adjacent), written as f16x2 (4 B).
// Split-bf16 MFMA: x = hi + lo, P = Ahi*Bhi + Alo*Bhi + Ahi*Blo  (~fp32 accurate);
// fp16 storage adds only ~0.05% rel error.
// Block = 64 nodes, wave w owns M-tile rows 16w..16w+15. 8 paired j-tiles:
// pair jp<4 -> Ps tiles (jp, jp+4); jp>=4 -> Pn tiles (jp+4, jp+8).
// ---------------------------------------------------------------------------
__global__ __launch_bounds__(256) void p_kernel(
    const float* __restrict__ node,
    const unsigned short* __restrict__ Bhi, const unsigned short* __restrict__ Blo,
    _Float16* __restrict__ Ps, _Float16* __restrict__ Pn)
{
    __shared__ float n_s[64 * 68];          // stride 68 floats: 2-way LDS aliasing only
    int tid = threadIdx.x;
    int base = blockIdx.x * 64;
    int cnt = min(64, NN - base);
    for (int i = tid; i < cnt * 64; i += 256) {
        int r = i >> 6, c = i & 63;
        n_s[r * 68 + c] = node[base * 64 + i];
    }
    __syncthreads();
    int w = tid >> 6, L = tid & 63, quad = L >> 4, lc = L & 15;
    const float* ap = &n_s[(16 * w + lc) * 68 + quad * 8];
    bf16x8 a0h, a0l, a1h, a1l;
    for (int t = 0; t < 8; ++t) {
        float x0 = ap[t];                   // k = quad*8 + t
        float x1 = ap[32 + t];              // k = 32 + quad*8 + t
        unsigned short h0 = f2bf(x0), h1 = f2bf(x1);
        a0h[t] = (short)h0; a1h[t] = (short)h1;
        a0l[t] = (short)f2bf(x0 - bf2f(h0));
        a1l[t] = (short)f2bf(x1 - bf2f(h1));
    }
    const bf16x8* bh = (const bf16x8*)Bhi;
    const bf16x8* bl = (const bf16x8*)Blo;
    #pragma unroll
    for (int jp = 0; jp < 8; ++jp) {
        int jf = (jp < 4) ? jp : (jp + 4);       // filter tile
        int jc = jf + 4;                         // core tile
        bf16x8 f0h = bh[(jf * 2 + 0) * 64 + L];
        bf16x8 f1h = bh[(jf * 2 + 1) * 64 + L];
        bf16x8 f0l = bl[(jf * 2 + 0) * 64 + L];
        bf16x8 f1l = bl[(jf * 2 + 1) * 64 + L];
        bf16x8 c0h = bh[(jc * 2 + 0) * 64 + L];
        bf16x8 c1h = bh[(jc * 2 + 1) * 64 + L];
        bf16x8 c0l = bl[(jc * 2 + 0) * 64 + L];
        bf16x8 c1l = bl[(jc * 2 + 1) * 64 + L];
        f32x4 Cf = {0.f, 0.f, 0.f, 0.f}, Cc = {0.f, 0.f, 0.f, 0.f};
        Cf = __builtin_amdgcn_mfma_f32_16x16x32_bf16(a0h, f0h, Cf, 0, 0, 0);
        Cf = __builtin_amdgcn_mfma_f32_16x16x32_bf16(a1h, f1h, Cf, 0, 0, 0);
        Cf = __builtin_amdgcn_mfma_f32_16x16x32_bf16(a0l, f0h, Cf, 0, 0, 0);
        Cf = __builtin_amdgcn_mfma_f32_16x16x32_bf16(a1l, f1h, Cf, 0, 0, 0);
        Cf = __builtin_amdgcn_mfma_f32_16x16x32_bf16(a0h, f0l, Cf, 0, 0, 0);
        Cf = __builtin_amdgcn_mfma_f32_16x16x32_bf16(a1h, f1l, Cf, 0, 0, 0);
        Cc = __builtin_amdgcn_mfma_f32_16x16x32_bf16(a0h, c0h, Cc, 0, 0, 0);
        Cc = __builtin_amdgcn_mfma_f32_16x16x32_bf16(a1h, c1h, Cc, 0, 0, 0);
        Cc = __builtin_amdgcn_mfma_f32_16x16x32_bf16(a0l, c0h, Cc, 0, 0, 0);
        Cc = __builtin_amdgcn_mfma_f32_16x16x32_bf16(a1l, c1h, Cc, 0, 0, 0);
        Cc = __builtin_amdgcn_mfma_f32_16x16x32_bf16(a0h, c0l, Cc, 0, 0, 0);
        Cc = __builtin_amdgcn_mfma_f32_16x16x32_bf16(a1h, c1l, Cc, 0, 0, 0);
        int cl = (jp < 4) ? (16 * jp + lc) : (16 * (jp - 4) + lc);   // col in [0,64)
        _Float16* P = (jp < 4) ? Ps : Pn;
        #pragma unroll
        for (int r = 0; r < 4; ++r) {
            int nr = 16 * w + quad * 4 + r;  // C layout: row = quad*4 + reg
            if (nr < cnt) {
                f16x2 v = {f2h_clamp(Cf[r]), f2h_clamp(Cc[r])};
                *(f16x2*)&P[(size_t)(base + nr) * 128 + 2 * cl] = v;
            }
        }
    }
}

// ---------------------------------------------------------------------------
// conv: one layer. Block = 16 nodes. Rolling m-loop (R4 structure: low VGPR,
// depth-1 prefetch). Per m:
//   C_edge(16 nodes x 128) = edge_tile_m @ Wc  (2 MFMA ksteps, K pad zeros in B)
//   gated = C_edge + Ps[self] + Pn[idx] + bias ; acc += sig(f)*softplus(c)
// Padded neighbors read the Pn sentinel row (filter=-60000 -> sigmoid=+0) so
// no mask ops in the loop. Gather = ds_read(precomputed gg<<8) + add + 4-B
// f16x2 load (one 64-B line per wave-quad-row).
// ---------------------------------------------------------------------------
__global__ __launch_bounds__(256) void conv_kernel(
    const float* __restrict__ node_in, const int* __restrict__ idx,
    const unsigned short* __restrict__ edge_tiles,
    const _Float16* __restrict__ Ps, const _Float16* __restrict__ Pn,
    const unsigned short* __restrict__ WcB, const float* __restrict__ bias_c,
    const float* __restrict__ alpha_p, float* __restrict__ node_out)
{
    __shared__ unsigned ofs_s[16 * 25];     // (gg<<8) per (node,m); stride 25
    int tid = threadIdx.x;
    int b = blockIdx.x;
    int base = b * 16;
    for (int i = tid; i < 16 * MM; i += 256) {
        int row = i / MM, m = i - row * MM;
        int g = idx[base * MM + i];
        unsigned gg = (unsigned)((g >= 0) ? g : NN);   // NN = sentinel row
        ofs_s[row * 25 + m] = gg << 8;                 // byte offset of Pn row
    }
    __syncthreads();

    int w = tid >> 6, L = tid & 63, quad = L >> 4, lc = L & 15;
    int colf = 16 * w + lc;                  // filter col (0..63) == output col
    const bf16x8* wcb = (const bf16x8*)WcB;
    bf16x8 bf0 = wcb[(w * 2 + 0) * 64 + L];        // filter tile j=w, kstep 0
    bf16x8 bf1 = wcb[(w * 2 + 1) * 64 + L];        // kstep 1 (k>=48 rows are zero)
    bf16x8 bc0 = wcb[((w + 4) * 2 + 0) * 64 + L];  // core tile j=w+4
    bf16x8 bc1 = wcb[((w + 4) * 2 + 1) * 64 + L];

    float bias_f = bias_c[colf];
    float bias_g = bias_c[64 + colf];
    float psb_f[4], psb_c[4];
    #pragma unroll
    for (int r = 0; r < 4; ++r) {
        int nr = base + quad * 4 + r;
        f16x2 sp = *(const f16x2*)&Ps[(size_t)nr * 128 + 2 * colf];
        psb_f[r] = (float)sp[0] + bias_f;
        psb_c[r] = (float)sp[1] + bias_g;
    }

    float acc[4] = {0.f, 0.f, 0.f, 0.f};
    const char* PnB = (const char*)Pn;
    unsigned coff = (unsigned)colf << 2;     // byte offset of the f16x2 pair in a row
    const unsigned* ofsr = &ofs_s[quad * 100];   // rows quad*4..+3, stride 25
    // A-frag base: row = lc, chunk = quad (kstep1 may read past the 48-elem row
    // for quad>=2 -- finite garbage nullified by zero B rows k>=48).
    const unsigned short* et = edge_tiles + (size_t)b * ETILE + lc * EROW + quad * 8;

    // ---- pipeline stage 0: prefetch m=0 ----
    f16x2 pn[4];
    #pragma unroll
    for (int r = 0; r < 4; ++r)
        pn[r] = *(const f16x2*)(PnB + (ofsr[r * 25] + coff));
    bf16x8 a0 = *(const bf16x8*)(et);
    bf16x8 a1 = *(const bf16x8*)(et + 32);

    for (int m = 0; m < MM - 1; ++m) {
        // ---- prefetch m+1 (latency hidden behind this iteration's compute) ----
        f16x2 pn2[4];
        #pragma unroll
        for (int r = 0; r < 4; ++r)
            pn2[r] = *(const f16x2*)(PnB + (ofsr[r * 25 + (m + 1)] + coff));
        const unsigned short* etn = et + (m + 1) * (16 * EROW);
        bf16x8 na0 = *(const bf16x8*)(etn);
        bf16x8 na1 = *(const bf16x8*)(etn + 32);
        // ---- compute m ----
        f32x4 Cf = {0.f, 0.f, 0.f, 0.f}, Cc = {0.f, 0.f, 0.f, 0.f};
        Cf = __builtin_amdgcn_mfma_f32_16x16x32_bf16(a0, bf0, Cf, 0, 0, 0);
        Cf = __builtin_amdgcn_mfma_f32_16x16x32_bf16(a1, bf1, Cf, 0, 0, 0);
        Cc = __builtin_amdgcn_mfma_f32_16x16x32_bf16(a0, bc0, Cc, 0, 0, 0);
        Cc = __builtin_amdgcn_mfma_f32_16x16x32_bf16(a1, bc1, Cc, 0, 0, 0);
        #pragma unroll
        for (int r = 0; r < 4; ++r) {
            float gf = Cf[r] + psb_f[r] + (float)pn[r][0];
            float gc = Cc[r] + psb_c[r] + (float)pn[r][1];
            float sg = 1.0f / (1.0f + __expf(-gf));   // sentinel: 1/(1+inf) = +0
            float sp = fmaxf(gc, 0.f) + __logf(1.0f + __expf(-fabsf(gc)));
            acc[r] += sg * sp;
        }
        // ---- rotate ----
        #pragma unroll
        for (int r = 0; r < 4; ++r) pn[r] = pn2[r];
        a0 = na0; a1 = na1;
    }
    {   // ---- epilogue: compute m = MM-1 ----
        f32x4 Cf = {0.f, 0.f, 0.f, 0.f}, Cc = {0.f, 0.f, 0.f, 0.f};
        Cf = __builtin_amdgcn_mfma_f32_16x16x32_bf16(a0, bf0, Cf, 0, 0, 0);
        Cf = __builtin_amdgcn_mfma_f32_16x16x32_bf16(a1, bf1, Cf, 0, 0, 0);
        Cc = __builtin_amdgcn_mfma_f32_16x16x32_bf16(a0, bc0, Cc, 0, 0, 0);
        Cc = __builtin_amdgcn_mfma_f32_16x16x32_bf16(a1, bc1, Cc, 0, 0, 0);
        #pragma unroll
        for (int r = 0; r < 4; ++r) {
            float gf = Cf[r] + psb_f[r] + (float)pn[r][0];
            float gc = Cc[r] + psb_c[r] + (float)pn[r][1];
            float sg = 1.0f / (1.0f + __expf(-gf));
            float sp = fmaxf(gc, 0.f) + __logf(1.0f + __expf(-fabsf(gc)));
            acc[r] += sg * sp;
        }
    }
    float alpha = alpha_p[0];
    #pragma unroll
    for (int r = 0; r < 4; ++r) {
        int nr = base + quad * 4 + r;
        float x = alpha * node_in[nr * 64 + colf] + acc[r];
        float o = fmaxf(x, 0.f) + __logf(1.0f + __expf(-fabsf(x)));
        node_out[nr * 64 + colf] = o;
    }
}

// ---------------------------------------------------------------------------
extern "C" void kernel_launch(void* const* d_in, const int* in_sizes, int n_in,
                              void* d_out, int out_size, void* d_ws, size_t ws_size,
                              hipStream_t stream)
{
    const float* node_fea = (const float*)d_in[0];
    const float* edge_fea = (const float*)d_in[1];
    const int*   eidx     = (const int*)d_in[2];
    const float* Wn = (const float*)d_in[3];
    const float* bn = (const float*)d_in[4];
    const float* We = (const float*)d_in[5];
    const float* be = (const float*)d_in[6];
    const float* W1 = (const float*)d_in[7];
    const float* b1 = (const float*)d_in[8];
    const float* a1 = (const float*)d_in[9];
    const float* W2 = (const float*)d_in[10];
    const float* b2 = (const float*)d_in[11];
    const float* a2 = (const float*)d_in[12];
    const float* W3 = (const float*)d_in[13];
    const float* b3 = (const float*)d_in[14];
    const float* a3 = (const float*)d_in[15];
    float* out = (float*)d_out;

    // Workspace layout (~167 MiB total)
    char* ws = (char*)d_ws;
    unsigned short* edge_tiles = (unsigned short*)ws;   // 115,200,000 B + 256 pad
    size_t off = 115200256;
    float* nodeA = (float*)(ws + off); off += 12800000;
    float* nodeB = (float*)(ws + off); off += 12800000;
    _Float16* Ps = (_Float16*)(ws + off); off += 12800000;
    _Float16* Pn = (_Float16*)(ws + off); off += 12800256;   // +256 B sentinel row
    unsigned short* WcB    = (unsigned short*)(ws + off); off += 3 * 8192 * 2;
    unsigned short* WsnBhi = (unsigned short*)(ws + off); off += 3 * 16384 * 2;
    unsigned short* WsnBlo = (unsigned short*)(ws + off); off += 3 * 16384 * 2;
    float* bias_c = (float*)(ws + off); off += 3 * 128 * 4;

    prep_kernel<<<dim3(72), dim3(256), 0, stream>>>(We, be, W1, b1, W2, b2, W3, b3,
                                                    WcB, WsnBhi, WsnBlo, bias_c, Pn);
    cast_kernel<<<dim3(2 * NBLK), dim3(256), 0, stream>>>(edge_fea, edge_tiles);
    embed_kernel<<<dim3(782), dim3(256), 0, stream>>>(node_fea, Wn, bn, nodeA);

    p_kernel<<<dim3(782), dim3(256), 0, stream>>>(nodeA, WsnBhi, WsnBlo, Ps, Pn);
    conv_kernel<<<dim3(NBLK), dim3(256), 0, stream>>>(nodeA, eidx, edge_tiles, Ps, Pn,
                                                      WcB, bias_c, a1, nodeB);

    p_kernel<<<dim3(782), dim3(256), 0, stream>>>(nodeB, WsnBhi + 16384, WsnBlo + 16384, Ps, Pn);
    conv_kernel<<<dim3(NBLK), dim3(256), 0, stream>>>(nodeB, eidx, edge_tiles, Ps, Pn,
                                                      WcB + 8192, bias_c + 128, a2, nodeA);

    p_kernel<<<dim3(782), dim3(256), 0, stream>>>(nodeA, WsnBhi + 32768, WsnBlo + 32768, Ps, Pn);
    conv_kernel<<<dim3(NBLK), dim3(256), 0, stream>>>(nodeA, eidx, edge_tiles, Ps, Pn,
                                                      WcB + 16384, bias_c + 256, a3, out);
}